// Round 5
// baseline (136.651 us; speedup 1.0000x reference)
//
#include <hip/hip_runtime.h>

#define HH   128
#define WW   128
#define HW   (HH * WW)
#define CC   64
#define TILE 8
#define HALO 12
#define NHP  (HALO * HALO)   // 144 halo pixels = 9 exact 16-px MFMA tiles

typedef unsigned int uint32;
typedef _Float16 h2   __attribute__((ext_vector_type(2)));  // packed arithmetic
typedef __fp16   h2b  __attribute__((ext_vector_type(2)));  // builtin interop
typedef _Float16 h8   __attribute__((ext_vector_type(8)));  // MFMA A/B frag
typedef float    f32x4 __attribute__((ext_vector_type(4))); // MFMA C/D frag

__device__ __forceinline__ uint32 pkrtz(float a, float b) {
    h2b r = __builtin_amdgcn_cvt_pkrtz(a, b);
    return __builtin_bit_cast(uint32, r);
}
__device__ __forceinline__ float dot2(uint32 a, uint32 b, float c) {
#if __has_builtin(__builtin_amdgcn_fdot2)
    return __builtin_amdgcn_fdot2(__builtin_bit_cast(h2b, a),
                                  __builtin_bit_cast(h2b, b), c, false);
#else
    h2 x = __builtin_bit_cast(h2, a), y = __builtin_bit_cast(h2, b);
    return c + (float)x.x * (float)y.x + (float)x.y * (float)y.y;
#endif
}
__device__ __forceinline__ f32x4 mfma16(uint4 a, uint4 b, f32x4 c) {
    return __builtin_amdgcn_mfma_f32_16x16x32_f16(
        __builtin_bit_cast(h8, a), __builtin_bit_cast(h8, b), c, 0, 0, 0);
}
// pack 8 consecutive fp32 -> 8 f16 (one A-fragment's lane data)
__device__ __forceinline__ uint4 pack_w8(const float* __restrict__ w) {
    const float4 lo = *(const float4*)w;
    const float4 hi = *(const float4*)(w + 4);
    uint4 r;
    r.x = pkrtz(lo.x, lo.y); r.y = pkrtz(lo.z, lo.w);
    r.z = pkrtz(hi.x, hi.y); r.w = pkrtz(hi.z, hi.w);
    return r;
}

// ---------------------------------------------------------------------------
// One fused kernel per 8x8 tile: stage x/y halo -> MFMA q/v conv (zero-OOB)
// -> scores/softmax/aggregate (dot2) -> MFMA final conv + bias + residual.
// LDS: 2 x 144 rows x 128 B (f16 channel-last, chunk^=(row&7) swizzle) = 36.9 KB.
// ---------------------------------------------------------------------------
__global__ __launch_bounds__(256, 4)
void fused_attn(const float* __restrict__ x, const float* __restrict__ y,
                const float* __restrict__ wx, const float* __restrict__ bx,
                const float* __restrict__ wy, const float* __restrict__ by,
                const float* __restrict__ wo, const float* __restrict__ bo,
                float* __restrict__ out)
{
    __shared__ uint32 qh[NHP * 32];  // y-halo, then q-halo, then agg(rows 0..63)
    __shared__ uint32 vh[NHP * 32];  // x-halo, then v-halo

    const int t   = threadIdx.x;
    const int b   = blockIdx.z;
    const int ty0 = blockIdx.y * TILE;
    const int tx0 = blockIdx.x * TILE;

    // ---- stage y/x halo as f16, swizzled channel-last ----
    for (int i = t; i < NHP * 8; i += 256) {
        const int c   = i / NHP;          // ic chunk (8 channels)
        const int pix = i - c * NHP;
        const int hy  = pix / HALO, hx = pix - hy * HALO;
        int gy = ty0 + hy - 2, gx = tx0 + hx - 2;
        const bool ok = ((unsigned)gy < HH) & ((unsigned)gx < WW);
        if (!ok) { gy = 0; gx = 0; }      // clamp; conv output zeroed later
        const size_t base = (size_t)b * CC * HW + (size_t)(c * 8) * HW
                          + (size_t)gy * WW + gx;
        float yv[8], xv[8];
        #pragma unroll
        for (int j = 0; j < 8; ++j) {
            yv[j] = y[base + (size_t)j * HW];
            xv[j] = x[base + (size_t)j * HW];
        }
        uint4 yq, xq;
        yq.x = pkrtz(yv[0], yv[1]); yq.y = pkrtz(yv[2], yv[3]);
        yq.z = pkrtz(yv[4], yv[5]); yq.w = pkrtz(yv[6], yv[7]);
        xq.x = pkrtz(xv[0], xv[1]); xq.y = pkrtz(xv[2], xv[3]);
        xq.z = pkrtz(xv[4], xv[5]); xq.w = pkrtz(xv[6], xv[7]);
        const int w0 = (c ^ (pix & 7)) * 4;
        *(uint4*)&qh[pix * 32 + w0] = yq;
        *(uint4*)&vh[pix * 32 + w0] = xq;
    }
    __syncthreads();

    const int wv = t >> 6;        // wave id = oc-tile
    const int ln = t & 63;
    const int lm = ln & 15;       // MFMA 16-index (A: m, B/D: n)
    const int qd = ln >> 4;       // quad

    // ---- q = wy*y + by over full halo (MFMA), wave wv: oc 16*wv.. ----
    {
        const uint4 a0 = pack_w8(wy + (wv * 16 + lm) * CC + qd * 8);
        const uint4 a1 = pack_w8(wy + (wv * 16 + lm) * CC + qd * 8 + 32);
        f32x4 acc[9];
        #pragma unroll
        for (int nt = 0; nt < 9; ++nt) {
            const int px = nt * 16 + lm, sw = px & 7;
            const uint4 b0 = *(const uint4*)&qh[px * 32 + ((qd    ) ^ sw) * 4];
            const uint4 b1 = *(const uint4*)&qh[px * 32 + ((qd + 4) ^ sw) * 4];
            f32x4 a = {0.f, 0.f, 0.f, 0.f};
            a = mfma16(a0, b0, a);
            a = mfma16(a1, b1, a);
            acc[nt] = a;
        }
        __syncthreads();   // all y-halo reads complete
        const float4 bq = *(const float4*)(by + wv * 16 + qd * 4);
        const int chunk = wv * 2 + (qd >> 1);
        #pragma unroll
        for (int nt = 0; nt < 9; ++nt) {
            const int px = nt * 16 + lm;
            const int hy = px / HALO, hx = px - hy * HALO;
            const int gy = ty0 + hy - 2, gx = tx0 + hx - 2;
            uint2 wp = {0u, 0u};   // OOB => q = 0 (unfold zero-pad semantics)
            if (((unsigned)gy < HH) & ((unsigned)gx < WW)) {
                wp.x = pkrtz(acc[nt].x + bq.x, acc[nt].y + bq.y);
                wp.y = pkrtz(acc[nt].z + bq.z, acc[nt].w + bq.w);
            }
            *(uint2*)&qh[px * 32 + (chunk ^ (px & 7)) * 4 + (qd & 1) * 2] = wp;
        }
    }

    // ---- v = wx*x + bx over full halo (MFMA) ----
    {
        const uint4 a0 = pack_w8(wx + (wv * 16 + lm) * CC + qd * 8);
        const uint4 a1 = pack_w8(wx + (wv * 16 + lm) * CC + qd * 8 + 32);
        f32x4 acc[9];
        #pragma unroll
        for (int nt = 0; nt < 9; ++nt) {
            const int px = nt * 16 + lm, sw = px & 7;
            const uint4 b0 = *(const uint4*)&vh[px * 32 + ((qd    ) ^ sw) * 4];
            const uint4 b1 = *(const uint4*)&vh[px * 32 + ((qd + 4) ^ sw) * 4];
            f32x4 a = {0.f, 0.f, 0.f, 0.f};
            a = mfma16(a0, b0, a);
            a = mfma16(a1, b1, a);
            acc[nt] = a;
        }
        __syncthreads();   // all x-halo reads complete (q-writes also done)
        const float4 bq = *(const float4*)(bx + wv * 16 + qd * 4);
        const int chunk = wv * 2 + (qd >> 1);
        #pragma unroll
        for (int nt = 0; nt < 9; ++nt) {
            const int px = nt * 16 + lm;
            const int hy = px / HALO, hx = px - hy * HALO;
            const int gy = ty0 + hy - 2, gx = tx0 + hx - 2;
            uint2 wp = {0u, 0u};
            if (((unsigned)gy < HH) & ((unsigned)gx < WW)) {
                wp.x = pkrtz(acc[nt].x + bq.x, acc[nt].y + bq.y);
                wp.y = pkrtz(acc[nt].z + bq.z, acc[nt].w + bq.w);
            }
            *(uint2*)&vh[px * 32 + (chunk ^ (px & 7)) * 4 + (qd & 1) * 2] = wp;
        }
    }
    __syncthreads();       // q,v halos visible

    // ---- scores: 4 lanes/px, 16 ch each, fdot2 (R4-verified) ----
    const int p    = t >> 2, sub = t & 3;
    const int py   = p >> 3, px8 = p & 7;
    const int crow = (py + 2) * HALO + (px8 + 2);

    uint32 qc[8];
    {
        const int c0 = ((2 * sub) ^ (crow & 7)) * 4;
        const int c1 = ((2 * sub + 1) ^ (crow & 7)) * 4;
        *(uint4*)&qc[0] = *(const uint4*)&qh[crow * 32 + c0];
        *(uint4*)&qc[4] = *(const uint4*)&qh[crow * 32 + c1];
    }

    float sc[25];
    #pragma unroll
    for (int dy = 0; dy < 5; ++dy)
        #pragma unroll
        for (int dx = 0; dx < 5; ++dx) {
            const int nrow = (py + dy) * HALO + (px8 + dx);
            const int c0 = ((2 * sub) ^ (nrow & 7)) * 4;
            const int c1 = ((2 * sub + 1) ^ (nrow & 7)) * 4;
            const uint4 r0 = *(const uint4*)&qh[nrow * 32 + c0];
            const uint4 r1 = *(const uint4*)&qh[nrow * 32 + c1];
            float s = 0.f;
            s = dot2(qc[0], r0.x, s); s = dot2(qc[1], r0.y, s);
            s = dot2(qc[2], r0.z, s); s = dot2(qc[3], r0.w, s);
            s = dot2(qc[4], r1.x, s); s = dot2(qc[5], r1.y, s);
            s = dot2(qc[6], r1.z, s); s = dot2(qc[7], r1.w, s);
            s += __shfl_xor(s, 1);
            s += __shfl_xor(s, 2);      // identical across the 4 sub-lanes
            sc[dy * 5 + dx] = s;
        }

    // ---- softmax over 25 ----
    float mx = sc[0];
    #pragma unroll
    for (int k = 1; k < 25; ++k) mx = fmaxf(mx, sc[k]);
    float sum = 0.f;
    #pragma unroll
    for (int k = 0; k < 25; ++k) { sc[k] = __expf(sc[k] - mx); sum += sc[k]; }
    const float inv = 1.f / sum;

    // ---- aggregate v (packed f16 fma) ----
    h2 ag[8];
    #pragma unroll
    for (int k = 0; k < 8; ++k) ag[k] = (h2)(_Float16)0;
    #pragma unroll
    for (int dy = 0; dy < 5; ++dy)
        #pragma unroll
        for (int dx = 0; dx < 5; ++dx) {
            const int nrow = (py + dy) * HALO + (px8 + dx);
            const int c0 = ((2 * sub) ^ (nrow & 7)) * 4;
            const int c1 = ((2 * sub + 1) ^ (nrow & 7)) * 4;
            const uint4 r0 = *(const uint4*)&vh[nrow * 32 + c0];
            const uint4 r1 = *(const uint4*)&vh[nrow * 32 + c1];
            const _Float16 af = (_Float16)(sc[dy * 5 + dx] * inv);
            const h2 a2 = {af, af};
            ag[0] += a2 * __builtin_bit_cast(h2, r0.x);
            ag[1] += a2 * __builtin_bit_cast(h2, r0.y);
            ag[2] += a2 * __builtin_bit_cast(h2, r0.z);
            ag[3] += a2 * __builtin_bit_cast(h2, r0.w);
            ag[4] += a2 * __builtin_bit_cast(h2, r1.x);
            ag[5] += a2 * __builtin_bit_cast(h2, r1.y);
            ag[6] += a2 * __builtin_bit_cast(h2, r1.z);
            ag[7] += a2 * __builtin_bit_cast(h2, r1.w);
        }

    __syncthreads();   // all waves past score/agg reads of qh
    {                  // agg -> qh rows 0..63 (same swizzled layout)
        const int c0 = ((2 * sub) ^ (p & 7)) * 4;
        const int c1 = ((2 * sub + 1) ^ (p & 7)) * 4;
        uint4 w0, w1;
        w0.x = __builtin_bit_cast(uint32, ag[0]); w0.y = __builtin_bit_cast(uint32, ag[1]);
        w0.z = __builtin_bit_cast(uint32, ag[2]); w0.w = __builtin_bit_cast(uint32, ag[3]);
        w1.x = __builtin_bit_cast(uint32, ag[4]); w1.y = __builtin_bit_cast(uint32, ag[5]);
        w1.z = __builtin_bit_cast(uint32, ag[6]); w1.w = __builtin_bit_cast(uint32, ag[7]);
        *(uint4*)&qh[p * 32 + c0] = w0;
        *(uint4*)&qh[p * 32 + c1] = w1;
    }
    __syncthreads();

    // ---- final conv (MFMA) + bias + residual, wave wv: oc 16*wv.. ----
    {
        const uint4 a0 = pack_w8(wo + (wv * 16 + lm) * CC + qd * 8);
        const uint4 a1 = pack_w8(wo + (wv * 16 + lm) * CC + qd * 8 + 32);
        const float4 bq = *(const float4*)(bo + wv * 16 + qd * 4);
        #pragma unroll
        for (int nt = 0; nt < 4; ++nt) {
            const int px = nt * 16 + lm, sw = px & 7;
            const uint4 b0 = *(const uint4*)&qh[px * 32 + ((qd    ) ^ sw) * 4];
            const uint4 b1 = *(const uint4*)&qh[px * 32 + ((qd + 4) ^ sw) * 4];
            f32x4 a = {0.f, 0.f, 0.f, 0.f};
            a = mfma16(a0, b0, a);
            a = mfma16(a1, b1, a);
            const int gh = ty0 + (px >> 3), gw = tx0 + (px & 7);
            const float av4[4] = {a.x + bq.x, a.y + bq.y, a.z + bq.z, a.w + bq.w};
            #pragma unroll
            for (int r = 0; r < 4; ++r) {
                const int oc = wv * 16 + qd * 4 + r;
                const size_t ad = (size_t)(b * CC + oc) * HW + (size_t)gh * WW + gw;
                out[ad] = av4[r] + x[ad];
            }
        }
    }
}

// ---------------------------------------------------------------------------
extern "C" void kernel_launch(void* const* d_in, const int* in_sizes, int n_in,
                              void* d_out, int out_size, void* d_ws, size_t ws_size,
                              hipStream_t stream) {
    const float* x  = (const float*)d_in[0];
    const float* y  = (const float*)d_in[1];
    const float* wx = (const float*)d_in[2];
    const float* bx = (const float*)d_in[3];
    const float* wy = (const float*)d_in[4];
    const float* by = (const float*)d_in[5];
    const float* wo = (const float*)d_in[6];
    const float* bo = (const float*)d_in[7];
    float* out = (float*)d_out;
    (void)d_ws; (void)ws_size;

    dim3 grid(WW / TILE, HH / TILE, 4);   // 16 x 16 x 4 = 1024 blocks
    fused_attn<<<grid, 256, 0, stream>>>(x, y, wx, bx, wy, by, wo, bo, out);
}

// Round 6
// 115.875 us; speedup vs baseline: 1.1793x; 1.1793x over previous
//
#include <hip/hip_runtime.h>

#define HH   128
#define WW   128
#define HW   (HH * WW)
#define CC   64
#define TILE 8
#define HALO 12
#define NHP  (HALO * HALO)   // 144 halo pixels = 9 exact 16-px MFMA tiles

typedef unsigned int uint32;
typedef _Float16 h2   __attribute__((ext_vector_type(2)));
typedef __fp16   h2b  __attribute__((ext_vector_type(2)));
typedef _Float16 h8   __attribute__((ext_vector_type(8)));
typedef float    f32x4 __attribute__((ext_vector_type(4)));

__device__ __forceinline__ uint32 pkrtz(float a, float b) {
    h2b r = __builtin_amdgcn_cvt_pkrtz(a, b);
    return __builtin_bit_cast(uint32, r);
}
__device__ __forceinline__ float dot2(uint32 a, uint32 b, float c) {
#if __has_builtin(__builtin_amdgcn_fdot2)
    return __builtin_amdgcn_fdot2(__builtin_bit_cast(h2b, a),
                                  __builtin_bit_cast(h2b, b), c, false);
#else
    h2 x = __builtin_bit_cast(h2, a), y = __builtin_bit_cast(h2, b);
    return c + (float)x.x * (float)y.x + (float)x.y * (float)y.y;
#endif
}
__device__ __forceinline__ f32x4 mfma16(uint4 a, uint4 b, f32x4 c) {
    return __builtin_amdgcn_mfma_f32_16x16x32_f16(
        __builtin_bit_cast(h8, a), __builtin_bit_cast(h8, b), c, 0, 0, 0);
}
__device__ __forceinline__ uint4 pack_w8(const float* __restrict__ w) {
    const float4 lo = *(const float4*)w;
    const float4 hi = *(const float4*)(w + 4);
    uint4 r;
    r.x = pkrtz(lo.x, lo.y); r.y = pkrtz(lo.z, lo.w);
    r.z = pkrtz(hi.x, hi.y); r.w = pkrtz(hi.z, hi.w);
    return r;
}

// ---------------------------------------------------------------------------
// Fused local attention, XCD-swizzled 1-D grid.
// A: y-halo -> q-halo -> agg(rows 0..63).  B: x-halo -> v-halo.
// Residual x saved to regs (f16) before v overwrites B. 5 barriers.
// ---------------------------------------------------------------------------
__global__ __launch_bounds__(256, 4)
void fused_attn(const float* __restrict__ x, const float* __restrict__ y,
                const float* __restrict__ wx, const float* __restrict__ bx,
                const float* __restrict__ wy, const float* __restrict__ by,
                const float* __restrict__ wo, const float* __restrict__ bo,
                float* __restrict__ out)
{
    __shared__ uint32 Ah[NHP * 32];
    __shared__ uint32 Bh[NHP * 32];

    // ---- XCD-aware tile mapping: lin%8 = XCD (round-robin heuristic);
    // each XCD owns a contiguous 64-row x 128-col half-batch region ----
    const int lin  = blockIdx.x;
    const int xcd  = lin & 7;
    const int rr   = lin >> 3;             // 0..127 within XCD
    const int b    = xcd >> 1;             // 2 XCDs per batch
    const int half = xcd & 1;              // top/bottom 8 tile-rows
    const int ty0  = (((rr >> 4) + half * 8)) * TILE;
    const int tx0  = (rr & 15) * TILE;

    const int t = threadIdx.x;

    // ---- stage y->A, x->B as f16, swizzled channel-last ----
    for (int i = t; i < NHP * 8; i += 256) {
        const int c   = i / NHP;
        const int pix = i - c * NHP;
        const int hy  = pix / HALO, hx = pix - hy * HALO;
        int gy = ty0 + hy - 2, gx = tx0 + hx - 2;
        const bool ok = ((unsigned)gy < HH) & ((unsigned)gx < WW);
        if (!ok) { gy = 0; gx = 0; }       // clamp; conv out zeroed at write
        const size_t base = (size_t)b * CC * HW + (size_t)(c * 8) * HW
                          + (size_t)gy * WW + gx;
        float yv[8], xv[8];
        #pragma unroll
        for (int j = 0; j < 8; ++j) {
            yv[j] = y[base + (size_t)j * HW];
            xv[j] = x[base + (size_t)j * HW];
        }
        uint4 yq, xq;
        yq.x = pkrtz(yv[0], yv[1]); yq.y = pkrtz(yv[2], yv[3]);
        yq.z = pkrtz(yv[4], yv[5]); yq.w = pkrtz(yv[6], yv[7]);
        xq.x = pkrtz(xv[0], xv[1]); xq.y = pkrtz(xv[2], xv[3]);
        xq.z = pkrtz(xv[4], xv[5]); xq.w = pkrtz(xv[6], xv[7]);
        const int w0 = (c ^ (pix & 7)) * 4;
        *(uint4*)&Ah[pix * 32 + w0] = yq;
        *(uint4*)&Bh[pix * 32 + w0] = xq;
    }
    __syncthreads();                                   // [1]

    const int wv = t >> 6;        // wave id = 16-oc tile
    const int ln = t & 63;
    const int lm = ln & 15;
    const int qd = ln >> 4;

    // ---- q-conv + v-conv (interleaved MFMA) + residual slice save ----
    f32x4 accq[9], accv[9];
    uint2 xres[4];
    {
        const uint4 aq0 = pack_w8(wy + (wv * 16 + lm) * CC + qd * 8);
        const uint4 aq1 = pack_w8(wy + (wv * 16 + lm) * CC + qd * 8 + 32);
        const uint4 av0 = pack_w8(wx + (wv * 16 + lm) * CC + qd * 8);
        const uint4 av1 = pack_w8(wx + (wv * 16 + lm) * CC + qd * 8 + 32);
        #pragma unroll
        for (int nt = 0; nt < 9; ++nt) {
            const int px = nt * 16 + lm, sw = px & 7;
            const uint4 b0 = *(const uint4*)&Ah[px * 32 + ((qd    ) ^ sw) * 4];
            const uint4 b1 = *(const uint4*)&Ah[px * 32 + ((qd + 4) ^ sw) * 4];
            f32x4 a = {0.f, 0.f, 0.f, 0.f};
            a = mfma16(aq0, b0, a); a = mfma16(aq1, b1, a); accq[nt] = a;
            const uint4 c0 = *(const uint4*)&Bh[px * 32 + ((qd    ) ^ sw) * 4];
            const uint4 c1 = *(const uint4*)&Bh[px * 32 + ((qd + 4) ^ sw) * 4];
            f32x4 v = {0.f, 0.f, 0.f, 0.f};
            v = mfma16(av0, c0, v); v = mfma16(av1, c1, v); accv[nt] = v;
        }
        #pragma unroll
        for (int nt = 0; nt < 4; ++nt) {   // f16 x at this lane's out pixels/chs
            const int px = nt * 16 + lm;
            const int hpix = ((px >> 3) + 2) * HALO + (px & 7) + 2;
            const int chunk = wv * 2 + (qd >> 1);
            xres[nt] = *(const uint2*)
                &Bh[hpix * 32 + (chunk ^ (hpix & 7)) * 4 + (qd & 1) * 2];
        }
    }
    __syncthreads();                                   // [2] halo reads done

    // ---- write q->A, v->B (OOB => 0: unfold zero-pad is AFTER conv+bias) ----
    {
        const float4 bq = *(const float4*)(by + wv * 16 + qd * 4);
        const float4 bv = *(const float4*)(bx + wv * 16 + qd * 4);
        const int chunk = wv * 2 + (qd >> 1);
        #pragma unroll
        for (int nt = 0; nt < 9; ++nt) {
            const int px = nt * 16 + lm;
            const int hy = px / HALO, hx = px - hy * HALO;
            const int gy = ty0 + hy - 2, gx = tx0 + hx - 2;
            uint2 wq = {0u, 0u}, wvv = {0u, 0u};
            if (((unsigned)gy < HH) & ((unsigned)gx < WW)) {
                wq.x  = pkrtz(accq[nt].x + bq.x, accq[nt].y + bq.y);
                wq.y  = pkrtz(accq[nt].z + bq.z, accq[nt].w + bq.w);
                wvv.x = pkrtz(accv[nt].x + bv.x, accv[nt].y + bv.y);
                wvv.y = pkrtz(accv[nt].z + bv.z, accv[nt].w + bv.w);
            }
            const int off = px * 32 + (chunk ^ (px & 7)) * 4 + (qd & 1) * 2;
            *(uint2*)&Ah[off] = wq;
            *(uint2*)&Bh[off] = wvv;
        }
    }
    __syncthreads();                                   // [3] q,v visible

    // ---- scores (from A) ----
    const int p    = t >> 2, sub = t & 3;
    const int py   = p >> 3, px8 = p & 7;
    const int crow = (py + 2) * HALO + (px8 + 2);

    uint32 qc[8];
    {
        const int c0 = ((2 * sub) ^ (crow & 7)) * 4;
        const int c1 = ((2 * sub + 1) ^ (crow & 7)) * 4;
        *(uint4*)&qc[0] = *(const uint4*)&Ah[crow * 32 + c0];
        *(uint4*)&qc[4] = *(const uint4*)&Ah[crow * 32 + c1];
    }

    float sc[25];
    #pragma unroll
    for (int dy = 0; dy < 5; ++dy)
        #pragma unroll
        for (int dx = 0; dx < 5; ++dx) {
            const int nrow = (py + dy) * HALO + (px8 + dx);
            const int c0 = ((2 * sub) ^ (nrow & 7)) * 4;
            const int c1 = ((2 * sub + 1) ^ (nrow & 7)) * 4;
            const uint4 r0 = *(const uint4*)&Ah[nrow * 32 + c0];
            const uint4 r1 = *(const uint4*)&Ah[nrow * 32 + c1];
            float s = 0.f;
            s = dot2(qc[0], r0.x, s); s = dot2(qc[1], r0.y, s);
            s = dot2(qc[2], r0.z, s); s = dot2(qc[3], r0.w, s);
            s = dot2(qc[4], r1.x, s); s = dot2(qc[5], r1.y, s);
            s = dot2(qc[6], r1.z, s); s = dot2(qc[7], r1.w, s);
            s += __shfl_xor(s, 1);
            s += __shfl_xor(s, 2);      // identical across the 4 sub-lanes
            sc[dy * 5 + dx] = s;
        }

    // ---- softmax over 25 ----
    float mx = sc[0];
    #pragma unroll
    for (int k = 1; k < 25; ++k) mx = fmaxf(mx, sc[k]);
    float sum = 0.f;
    #pragma unroll
    for (int k = 0; k < 25; ++k) { sc[k] = __expf(sc[k] - mx); sum += sc[k]; }
    const float inv = 1.f / sum;

    // ---- aggregate v (from B, packed f16 fma) ----
    h2 ag[8];
    #pragma unroll
    for (int k = 0; k < 8; ++k) ag[k] = (h2)(_Float16)0;
    #pragma unroll
    for (int dy = 0; dy < 5; ++dy)
        #pragma unroll
        for (int dx = 0; dx < 5; ++dx) {
            const int nrow = (py + dy) * HALO + (px8 + dx);
            const int c0 = ((2 * sub) ^ (nrow & 7)) * 4;
            const int c1 = ((2 * sub + 1) ^ (nrow & 7)) * 4;
            const uint4 r0 = *(const uint4*)&Bh[nrow * 32 + c0];
            const uint4 r1 = *(const uint4*)&Bh[nrow * 32 + c1];
            const _Float16 af = (_Float16)(sc[dy * 5 + dx] * inv);
            const h2 a2 = {af, af};
            ag[0] += a2 * __builtin_bit_cast(h2, r0.x);
            ag[1] += a2 * __builtin_bit_cast(h2, r0.y);
            ag[2] += a2 * __builtin_bit_cast(h2, r0.z);
            ag[3] += a2 * __builtin_bit_cast(h2, r0.w);
            ag[4] += a2 * __builtin_bit_cast(h2, r1.x);
            ag[5] += a2 * __builtin_bit_cast(h2, r1.y);
            ag[6] += a2 * __builtin_bit_cast(h2, r1.z);
            ag[7] += a2 * __builtin_bit_cast(h2, r1.w);
        }

    __syncthreads();                                   // [4] A reads done
    {                 // agg -> A rows 0..63 (same swizzled layout)
        const int c0 = ((2 * sub) ^ (p & 7)) * 4;
        const int c1 = ((2 * sub + 1) ^ (p & 7)) * 4;
        uint4 w0, w1;
        w0.x = __builtin_bit_cast(uint32, ag[0]); w0.y = __builtin_bit_cast(uint32, ag[1]);
        w0.z = __builtin_bit_cast(uint32, ag[2]); w0.w = __builtin_bit_cast(uint32, ag[3]);
        w1.x = __builtin_bit_cast(uint32, ag[4]); w1.y = __builtin_bit_cast(uint32, ag[5]);
        w1.z = __builtin_bit_cast(uint32, ag[6]); w1.w = __builtin_bit_cast(uint32, ag[7]);
        *(uint4*)&Ah[p * 32 + c0] = w0;
        *(uint4*)&Ah[p * 32 + c1] = w1;
    }
    __syncthreads();                                   // [5]

    // ---- final conv (MFMA) + bias + f16 residual from regs ----
    {
        const uint4 a0 = pack_w8(wo + (wv * 16 + lm) * CC + qd * 8);
        const uint4 a1 = pack_w8(wo + (wv * 16 + lm) * CC + qd * 8 + 32);
        const float4 bq = *(const float4*)(bo + wv * 16 + qd * 4);
        #pragma unroll
        for (int nt = 0; nt < 4; ++nt) {
            const int px = nt * 16 + lm, sw = px & 7;
            const uint4 b0 = *(const uint4*)&Ah[px * 32 + ((qd    ) ^ sw) * 4];
            const uint4 b1 = *(const uint4*)&Ah[px * 32 + ((qd + 4) ^ sw) * 4];
            f32x4 a = {0.f, 0.f, 0.f, 0.f};
            a = mfma16(a0, b0, a);
            a = mfma16(a1, b1, a);
            const int gh = ty0 + (px >> 3), gw = tx0 + (px & 7);
            const h2 xp0 = __builtin_bit_cast(h2, xres[nt].x);  // ch qd*4+0,1
            const h2 xp1 = __builtin_bit_cast(h2, xres[nt].y);  // ch qd*4+2,3
            const float rv[4] = {(float)xp0.x, (float)xp0.y,
                                 (float)xp1.x, (float)xp1.y};
            const float av4[4] = {a.x + bq.x, a.y + bq.y, a.z + bq.z, a.w + bq.w};
            #pragma unroll
            for (int r = 0; r < 4; ++r) {
                const int oc = wv * 16 + qd * 4 + r;
                const size_t ad = (size_t)(b * CC + oc) * HW + (size_t)gh * WW + gw;
                out[ad] = av4[r] + rv[r];
            }
        }
    }
}

// ---------------------------------------------------------------------------
extern "C" void kernel_launch(void* const* d_in, const int* in_sizes, int n_in,
                              void* d_out, int out_size, void* d_ws, size_t ws_size,
                              hipStream_t stream) {
    const float* x  = (const float*)d_in[0];
    const float* y  = (const float*)d_in[1];
    const float* wx = (const float*)d_in[2];
    const float* bx = (const float*)d_in[3];
    const float* wy = (const float*)d_in[4];
    const float* by = (const float*)d_in[5];
    const float* wo = (const float*)d_in[6];
    const float* bo = (const float*)d_in[7];
    float* out = (float*)d_out;
    (void)d_ws; (void)ws_size;

    fused_attn<<<dim3(1024), 256, 0, stream>>>(x, y, wx, bx, wy, by, wo, bo, out);
}